// Round 4
// baseline (1418.794 us; speedup 1.0000x reference)
//
#include <hip/hip_runtime.h>
#include <hip/hip_fp16.h>

#define NH 4      // heads
#define CH 64     // channels/head
#define PPART 8   // src slices; fp16 slice = N/8 rows * 512B ~ 3.2MB < 4MB XCD L2

// ---------------- encoder: h = relu(x @ W + b); x:[N,8], W:[8,64] ----------------
__global__ void encoder_kernel(const float* __restrict__ x, const float* __restrict__ W,
                               const float* __restrict__ b, float* __restrict__ h, int N) {
  int idx = blockIdx.x * blockDim.x + threadIdx.x;
  if (idx >= N * 64) return;
  int n = idx >> 6, j = idx & 63;
  const float* xp = x + n * 8;
  float acc = b[j];
#pragma unroll
  for (int k = 0; k < 8; ++k) acc = fmaf(xp[k], W[k * 64 + j], acc);
  h[idx] = fmaxf(acc, 0.0f);
}

// ---------------- xl = h@Wl + bl, xr = h@Wr + br; both stored fp16 ----------------
// xl is the random-gather table (512B rows); xr feeds only the alpha nonlinearity.
template <int K>
__global__ void lin_lr_kernel(const float* __restrict__ h,
                              const float* __restrict__ Wl, const float* __restrict__ bl,
                              const float* __restrict__ Wr, const float* __restrict__ br,
                              __half* __restrict__ xl, __half* __restrict__ xr, int N) {
  __shared__ float hs[8][K];
  int n0 = blockIdx.x * 8;
  int j = threadIdx.x;  // output column
  int nmax = N - n0; if (nmax > 8) nmax = 8;
  for (int idx = j; idx < nmax * K; idx += 256) {
    int m = idx / K, k = idx % K;
    hs[m][k] = h[(size_t)(n0 + m) * K + k];
  }
  __syncthreads();
  float accl[8], accr[8];
  float bjl = bl[j], bjr = br[j];
#pragma unroll
  for (int m = 0; m < 8; ++m) { accl[m] = bjl; accr[m] = bjr; }
  for (int k = 0; k < K; ++k) {
    float wl = Wl[k * 256 + j];
    float wr = Wr[k * 256 + j];
#pragma unroll
    for (int m = 0; m < 8; ++m) {
      accl[m] = fmaf(hs[m][k], wl, accl[m]);
      accr[m] = fmaf(hs[m][k], wr, accr[m]);
    }
  }
  for (int m = 0; m < nmax; ++m) {
    xl[(size_t)(n0 + m) * 256 + j] = __float2half_rn(accl[m]);
    xr[(size_t)(n0 + m) * 256 + j] = __float2half_rn(accr[m]);
  }
}

// ---------------- CSR build, counting sort keyed (dst*8 + src_slice) ----------------
__global__ void hist2_kernel(const int* __restrict__ src, const int* __restrict__ dst,
                             int* __restrict__ deg2, int E, int psz) {
  int e = blockIdx.x * blockDim.x + threadIdx.x;
  if (e < E) atomicAdd(&deg2[dst[e] * PPART + src[e] / psz], 1);
}

// A: per-block sum of 2048 deg entries (256 thr x 8)
__global__ void scan_partial2_kernel(const int* __restrict__ deg, int* __restrict__ partial, int M) {
  __shared__ int sm[256];
  int t = threadIdx.x;
  int base = blockIdx.x * 2048 + t * 8;
  int s = 0;
#pragma unroll
  for (int k = 0; k < 8; ++k) { int i = base + k; s += (i < M) ? deg[i] : 0; }
  sm[t] = s;
  __syncthreads();
#pragma unroll
  for (int st = 128; st > 0; st >>= 1) {
    if (t < st) sm[t] += sm[t + st];
    __syncthreads();
  }
  if (t == 0) partial[blockIdx.x] = sm[0];
}

// B: single-block exclusive scan of the (<=256) partials
__global__ void scan_offsets_kernel(int* __restrict__ partial, int nb) {
  __shared__ int sm[256];
  int t = threadIdx.x;
  int v = (t < nb) ? partial[t] : 0;
  sm[t] = v;
  __syncthreads();
#pragma unroll
  for (int off = 1; off < 256; off <<= 1) {
    int a = (t >= off) ? sm[t - off] : 0;
    __syncthreads();
    sm[t] += a;
    __syncthreads();
  }
  if (t < nb) partial[t] = sm[t] - v;  // exclusive
}

// C: per-block scan of 2048 entries + block offset -> rowptr2/cursor2 (in-place safe:
// each block reads its own range into registers before writing)
__global__ void scan_final2_kernel(const int* __restrict__ deg, const int* __restrict__ partial,
                                   int* __restrict__ rowptr, int* __restrict__ cursor, int M, int E) {
  __shared__ int sm[256];
  int t = threadIdx.x;
  int base = blockIdx.x * 2048 + t * 8;
  int v[8]; int s = 0;
#pragma unroll
  for (int k = 0; k < 8; ++k) { int i = base + k; v[k] = (i < M) ? deg[i] : 0; s += v[k]; }
  sm[t] = s;
  __syncthreads();
#pragma unroll
  for (int off = 1; off < 256; off <<= 1) {
    int a = (t >= off) ? sm[t - off] : 0;
    __syncthreads();
    sm[t] += a;
    __syncthreads();
  }
  int run = partial[blockIdx.x] + sm[t] - s;  // exclusive base for this thread's 8
#pragma unroll
  for (int k = 0; k < 8; ++k) {
    int i = base + k;
    if (i < M) { rowptr[i] = run; cursor[i] = run; run += v[k]; }
  }
  if (blockIdx.x == 0 && t == 0) rowptr[M] = E;
}

__global__ void scatter_build2_kernel(const int* __restrict__ src, const int* __restrict__ dst,
                                      const float* __restrict__ ea, int* __restrict__ cursor,
                                      int* __restrict__ srcs, float* __restrict__ eas, int E, int psz) {
  int e = blockIdx.x * blockDim.x + threadIdx.x;
  if (e >= E) return;
  int s = src[e];
  int key = dst[e] * PPART + s / psz;
  int pos = atomicAdd(&cursor[key], 1);
  srcs[pos] = s;
  eas[pos] = ea[e];
}

// ---------------- helpers: fp16x4 <-> float4 ----------------
__device__ __forceinline__ float4 ldh4(const uint2* __restrict__ p, size_t idx) {
  uint2 r = p[idx];
  __half2 a = *reinterpret_cast<const __half2*>(&r.x);
  __half2 b = *reinterpret_cast<const __half2*>(&r.y);
  float2 fa = __half22float2(a);
  float2 fb = __half22float2(b);
  return make_float4(fa.x, fa.y, fb.x, fb.y);
}

__device__ __forceinline__ uint2 sth4(float4 v) {
  __half2 a = __floats2half2_rn(v.x, v.y);
  __half2 b = __floats2half2_rn(v.z, v.w);
  uint2 r;
  r.x = *reinterpret_cast<unsigned*>(&a);
  r.y = *reinterpret_cast<unsigned*>(&b);
  return r;
}

// ---------------- per-edge alpha + accumulate (unchanged math) ----------------
__device__ __forceinline__ void edge_accum(const float4 xlv, const float eav,
                                           const float4 xr4, const float4 We4, const float4 at4,
                                           float4& acc, float& denom) {
  float4 v;
  v.x = fmaf(eav, We4.x, xlv.x + xr4.x);
  v.y = fmaf(eav, We4.y, xlv.y + xr4.y);
  v.z = fmaf(eav, We4.z, xlv.z + xr4.z);
  v.w = fmaf(eav, We4.w, xlv.w + xr4.w);
  v.x = (v.x >= 0.f) ? v.x : 0.2f * v.x;
  v.y = (v.y >= 0.f) ? v.y : 0.2f * v.y;
  v.z = (v.z >= 0.f) ? v.z : 0.2f * v.z;
  v.w = (v.w >= 0.f) ? v.w : 0.2f * v.w;
  float p = v.x * at4.x + v.y * at4.y + v.z * at4.z + v.w * at4.w;
  p += __shfl_xor(p, 1, 64);
  p += __shfl_xor(p, 2, 64);
  p += __shfl_xor(p, 4, 64);
  p += __shfl_xor(p, 8, 64);   // all 16 lanes of the head group hold alpha_h
  float ex = __expf(p);
  denom += ex;
  acc.x = fmaf(ex, xlv.x, acc.x);
  acc.y = fmaf(ex, xlv.y, acc.y);
  acc.z = fmaf(ex, xlv.z, acc.z);
  acc.w = fmaf(ex, xlv.w, acc.w);
}

// ---------------- phase A: per-(node, src-slice) partial softmax ----------------
// Block b -> slice s = b%8 (XCD-affine under round-robin dispatch), 4 waves = 4 nodes.
// Every gather in this block targets one 3.2MB slice -> L2-resident wherever it runs.
// Stores mean = acc/denom (fp16; convex combination of xl -> no overflow) + denom fp32.
// Exact decomposition: out = sum_s denom_s*mean_s / sum_s denom_s.
__global__ void gat_partial_kernel(const int* __restrict__ rowptr2,
                                   const int* __restrict__ srcs,
                                   const float* __restrict__ eas,
                                   const __half* __restrict__ xl,
                                   const __half* __restrict__ xr,
                                   const float* __restrict__ We,
                                   const float* __restrict__ att,
                                   uint2* __restrict__ Pacc,
                                   float* __restrict__ denomP,
                                   int chunk0, int Nc, int cap) {
  int b = blockIdx.x;
  int s = b & 7;                  // slice
  int nb = b >> 3;
  int w = threadIdx.x >> 6;
  int lane = threadIdx.x & 63;
  int ln = nb * 4 + w;            // node index within chunk
  if (ln >= Nc) return;
  int d = chunk0 + ln;
  const uint2* xlh = (const uint2*)xl;
  const uint2* xrh = (const uint2*)xr;
  float4 xr4 = ldh4(xrh, (size_t)d * 64 + lane);
  float4 We4 = ((const float4*)We)[lane];
  float4 at4 = ((const float4*)att)[lane];
  int beg = rowptr2[d * PPART + s], end = rowptr2[d * PPART + s + 1];
  float4 acc = {0.f, 0.f, 0.f, 0.f};
  float denom = 0.f;
  int i = beg;
  for (; i + 1 < end; i += 2) {
    int s0 = srcs[i], s1 = srcs[i + 1];
    float e0 = eas[i], e1 = eas[i + 1];
    float4 a0 = ldh4(xlh, (size_t)s0 * 64 + lane);
    float4 a1 = ldh4(xlh, (size_t)s1 * 64 + lane);
    edge_accum(a0, e0, xr4, We4, at4, acc, denom);
    edge_accum(a1, e1, xr4, We4, at4, acc, denom);
  }
  if (i < end) {
    float4 a0 = ldh4(xlh, (size_t)srcs[i] * 64 + lane);
    edge_accum(a0, eas[i], xr4, We4, at4, acc, denom);
  }
  float inv = (denom > 0.f) ? (1.f / denom) : 0.f;
  float4 m = make_float4(acc.x * inv, acc.y * inv, acc.z * inv, acc.w * inv);
  size_t slot = (size_t)s * cap + ln;
  Pacc[slot * 64 + lane] = sth4(m);
  if ((lane & 15) == 0) denomP[slot * 4 + (lane >> 4)] = denom;
}

// ---------------- phase B: combine 8 slice-partials per node ----------------
template <bool POOL>
__global__ void gat_reduce_kernel(const uint2* __restrict__ Pacc,
                                  const float* __restrict__ denomP,
                                  const float* __restrict__ bias,
                                  float* __restrict__ out,
                                  const int* __restrict__ batch,
                                  float* __restrict__ sums,
                                  float* __restrict__ cnt,
                                  int chunk0, int Nc, int cap) {
  int w = threadIdx.x >> 6;
  int lane = threadIdx.x & 63;
  int ln = blockIdx.x * 4 + w;
  if (ln >= Nc) return;
  int d = chunk0 + ln;
  int h = lane >> 4;
  float4 acc = {0.f, 0.f, 0.f, 0.f};
  float D = 0.f;
#pragma unroll
  for (int s = 0; s < PPART; ++s) {
    size_t slot = (size_t)s * cap + ln;
    float ds = denomP[slot * 4 + h];
    float4 m = ldh4(Pacc, slot * 64 + lane);
    D += ds;
    acc.x = fmaf(ds, m.x, acc.x);
    acc.y = fmaf(ds, m.y, acc.y);
    acc.z = fmaf(ds, m.z, acc.z);
    acc.w = fmaf(ds, m.w, acc.w);
  }
  float inv = 1.f / (D + 1e-16f);
  float4 b4 = ((const float4*)bias)[lane];
  float4 o;
  o.x = fmaxf(fmaf(acc.x, inv, b4.x), 0.f);
  o.y = fmaxf(fmaf(acc.y, inv, b4.y), 0.f);
  o.z = fmaxf(fmaf(acc.z, inv, b4.z), 0.f);
  o.w = fmaxf(fmaf(acc.w, inv, b4.w), 0.f);
  if (POOL) {
    int g = batch[d];
    float* sg = sums + (size_t)g * 256 + lane * 4;
    atomicAdd(sg + 0, o.x);
    atomicAdd(sg + 1, o.y);
    atomicAdd(sg + 2, o.z);
    atomicAdd(sg + 3, o.w);
    if (lane == 0) atomicAdd(&cnt[g], 1.0f);
  } else {
    ((float4*)out)[(size_t)d * 64 + lane] = o;
  }
}

// ---------------- per-graph MLP head ----------------
__global__ void mlp_kernel(const float* __restrict__ sums, const float* __restrict__ cnt,
                           const float* __restrict__ p1W, const float* __restrict__ p1b,
                           const float* __restrict__ lng, const float* __restrict__ lnb,
                           const float* __restrict__ p2W, const float* __restrict__ p2b,
                           float* __restrict__ outp, int G) {
  __shared__ float p[256];
  __shared__ float z[128];
  __shared__ float wsum[2];
  __shared__ float wsum2[2];
  int g = blockIdx.x;
  int t = threadIdx.x;  // 0..127
  float c = fmaxf(cnt[g], 1.0f);
  p[t] = sums[(size_t)g * 256 + t] / c;
  p[t + 128] = sums[(size_t)g * 256 + t + 128] / c;
  __syncthreads();
  float acc = p1b[t];
  for (int k = 0; k < 256; ++k) acc = fmaf(p[k], p1W[k * 128 + t], acc);
  float v = acc;
#pragma unroll
  for (int off = 32; off > 0; off >>= 1) v += __shfl_xor(v, off, 64);
  if ((t & 63) == 0) wsum[t >> 6] = v;
  __syncthreads();
  float mu = (wsum[0] + wsum[1]) * (1.0f / 128.0f);
  float dv = acc - mu;
  float vv = dv * dv;
#pragma unroll
  for (int off = 32; off > 0; off >>= 1) vv += __shfl_xor(vv, off, 64);
  if ((t & 63) == 0) wsum2[t >> 6] = vv;
  __syncthreads();
  float var = (wsum2[0] + wsum2[1]) * (1.0f / 128.0f);
  float zv = dv * rsqrtf(var + 1e-5f) * lng[t] + lnb[t];
  z[t] = fmaxf(zv, 0.0f);
  __syncthreads();
  if (t < 64) {
    float o = p2b[t];
    for (int k = 0; k < 128; ++k) o = fmaf(z[k], p2W[k * 64 + t], o);
    outp[(size_t)g * 64 + t] = fmaxf(o, 0.0f);
  }
}

extern "C" void kernel_launch(void* const* d_in, const int* in_sizes, int n_in,
                              void* d_out, int out_size, void* d_ws, size_t ws_size,
                              hipStream_t stream) {
  const float* x      = (const float*)d_in[0];
  const int*   ei     = (const int*)d_in[1];
  const float* ea     = (const float*)d_in[2];
  const int*   batch  = (const int*)d_in[3];
  const float* enc_W  = (const float*)d_in[4];
  const float* enc_b  = (const float*)d_in[5];
  const float* Wl1    = (const float*)d_in[6];
  const float* bl1    = (const float*)d_in[7];
  const float* Wr1    = (const float*)d_in[8];
  const float* br1    = (const float*)d_in[9];
  const float* We1    = (const float*)d_in[10];
  const float* att1   = (const float*)d_in[11];
  const float* bias1  = (const float*)d_in[12];
  const float* Wl2    = (const float*)d_in[13];
  const float* bl2    = (const float*)d_in[14];
  const float* Wr2    = (const float*)d_in[15];
  const float* br2    = (const float*)d_in[16];
  const float* We2    = (const float*)d_in[17];
  const float* att2   = (const float*)d_in[18];
  const float* bias2  = (const float*)d_in[19];
  const float* p1W    = (const float*)d_in[20];
  const float* p1b    = (const float*)d_in[21];
  const float* lng    = (const float*)d_in[22];
  const float* lnb    = (const float*)d_in[23];
  const float* p2W    = (const float*)d_in[24];
  const float* p2b    = (const float*)d_in[25];
  float* outp = (float*)d_out;

  int N = in_sizes[0] / 8;
  int E = in_sizes[2];
  int G = out_size / 64;
  const int* src = ei;
  const int* dst = ei + E;
  int M = N * PPART;                 // 8N keys
  int psz = (N + PPART - 1) / PPART; // src rows per slice
  int nb2 = (M + 2047) / 2048;       // scan blocks over M (<=256; 400k -> 196)

  // ---- workspace layout (base ~125MB, strictly below the proven 173MB footprint) ----
  float* ws      = (float*)d_ws;
  float* h0      = ws;                          // N*64 f32
  __half* xlh    = (__half*)(h0 + (size_t)N * 64);        // N*256 fp16 (N*128 f32 words)
  __half* xrh    = (__half*)((float*)xlh + (size_t)N * 128); // N*256 fp16
  float* B2      = (float*)xrh + (size_t)N * 128;          // N*256 f32 (layer1 out)
  float* eas     = B2     + (size_t)N * 256;    // E floats (sorted edge attr)
  float* sums    = eas    + (size_t)E;          // G*256
  float* cnt     = sums   + (size_t)G * 256;    // G
  int*   srcs    = (int*)(cnt + G);             // E ints (sorted src)
  int*   rowptr2 = srcs + (size_t)E;            // M+1
  int*   cursor2 = rowptr2 + (size_t)(M + 1);   // M (doubles as deg2 histogram)
  int*   partial = cursor2 + (size_t)M;         // nb2 (<=256)
  // partial-results region, sized adaptively from the REMAINING workspace
  char*  pbase_c = (char*)(partial + 256);
  size_t used    = (size_t)(pbase_c - (char*)d_ws);
  used           = (used + 15) & ~(size_t)15;   // 16B align
  size_t avail   = (ws_size > used) ? (ws_size - used) : 0;
  // per-node partial bytes: 8 slices * (64 lanes * 8B mean + 16B denom) = 4224
  int cap = (int)(avail / 4224);
  if (cap > N) cap = N;
  if (cap < 1) cap = 1;               // degenerate; base layout << proven ws so won't happen
  uint2* Pacc    = (uint2*)((char*)d_ws + used);          // cap*8*64 uint2 = cap*4096B
  float* denomP  = (float*)((char*)Pacc + (size_t)cap * 4096); // cap*8*4 f32 = cap*128B

  // encoder
  encoder_kernel<<<(N * 64 + 255) / 256, 256, 0, stream>>>(x, enc_W, enc_b, h0, N);

  // CSR build keyed (dst, src-slice) — shared by both layers (edge_index static)
  hipMemsetAsync(cursor2, 0, (size_t)M * sizeof(int), stream);
  hist2_kernel<<<(E + 255) / 256, 256, 0, stream>>>(src, dst, cursor2, E, psz);
  scan_partial2_kernel<<<nb2, 256, 0, stream>>>(cursor2, partial, M);
  scan_offsets_kernel<<<1, 256, 0, stream>>>(partial, nb2);
  scan_final2_kernel<<<nb2, 256, 0, stream>>>(cursor2, partial, rowptr2, cursor2, M, E);
  scatter_build2_kernel<<<(E + 255) / 256, 256, 0, stream>>>(src, dst, ea, cursor2, srcs, eas, E, psz);

  // GAT layer 1 (K=64): h0 -> B2
  lin_lr_kernel<64><<<(N + 7) / 8, 256, 0, stream>>>(h0, Wl1, bl1, Wr1, br1, xlh, xrh, N);
  for (int c0 = 0; c0 < N; c0 += cap) {
    int Nc = N - c0; if (Nc > cap) Nc = cap;
    int nblk = (Nc + 3) / 4;
    gat_partial_kernel<<<nblk * PPART, 256, 0, stream>>>(
        rowptr2, srcs, eas, xlh, xrh, We1, att1, Pacc, denomP, c0, Nc, cap);
    gat_reduce_kernel<false><<<nblk, 256, 0, stream>>>(
        Pacc, denomP, bias1, B2, nullptr, nullptr, nullptr, c0, Nc, cap);
  }

  // GAT layer 2 (K=256): B2 -> pooled sums directly
  lin_lr_kernel<256><<<(N + 7) / 8, 256, 0, stream>>>(B2, Wl2, bl2, Wr2, br2, xlh, xrh, N);
  hipMemsetAsync(sums, 0, ((size_t)G * 256 + G) * sizeof(float), stream);
  for (int c0 = 0; c0 < N; c0 += cap) {
    int Nc = N - c0; if (Nc > cap) Nc = cap;
    int nblk = (Nc + 3) / 4;
    gat_partial_kernel<<<nblk * PPART, 256, 0, stream>>>(
        rowptr2, srcs, eas, xlh, xrh, We2, att2, Pacc, denomP, c0, Nc, cap);
    gat_reduce_kernel<true><<<nblk, 256, 0, stream>>>(
        Pacc, denomP, bias2, nullptr, batch, sums, cnt, c0, Nc, cap);
  }

  // per-graph MLP
  mlp_kernel<<<G, 128, 0, stream>>>(sums, cnt, p1W, p1b, lng, lnb, p2W, p2b, outp, G);
}